// Round 9
// baseline (335.711 us; speedup 1.0000x reference)
//
#include <hip/hip_runtime.h>
#include <hip/hip_bf16.h>
#include <math.h>

// Swin Transformer 3D block, MI355X (gfx950).  R9.
// vs R8: weights read ONCE per block via LDS staging (Wq staged during LN1;
// proj + per-hc fc1/fc2 double-buffered in the dead Kb/vT region, wave 7 is
// the producer wave in the MLP loop); biasM stored bf16; res kept in regs
// (VGPR headroom 64->~112); direct final stores (no OutF bounce).

#define NTOK 98
#define SCALE 0.17677669529663687f

// fragment ids (x512 elems): qkv 0..53, proj 54..71, fc1 72..143, fc2 144..215
// fc2 grouped by hc: frag = FR_FC2 + (hc*6+nt)*2 + p
#define FR_PROJ 54
#define FR_FC1  72
#define FR_FC2  144
#define WS_BF16_N 110592
#define WS_BIASM_BYTE 221184
#define WS_NEED   296448

typedef __attribute__((ext_vector_type(8))) short bf16x8;
typedef __attribute__((ext_vector_type(4))) float f32x4;

__device__ __forceinline__ int row_of(int wid, int t) {
    int b = wid >> 8, rem = wid & 255;
    int d0 = rem >> 6, h0 = (rem >> 3) & 7, w0 = rem & 7;
    int td = t / 49, tr = t % 49, th = tr / 7, tw = tr % 7;
    int dd = d0 * 2 + td, hh = h0 * 7 + th, ww = w0 * 7 + tw;
    return ((b * 8 + dd) * 56 + hh) * 56 + ww;
}

__device__ __forceinline__ int pcode(int t) {
    int a = t / 49, r = t - 49 * a, b = r / 7, c = r - 7 * b;
    return a * 169 + b * 13 + c;
}

__device__ __forceinline__ unsigned short f2bfu(float f) {
    __hip_bfloat16 h = __float2bfloat16(f);
    unsigned short u; __builtin_memcpy(&u, &h, 2); return u;
}
__device__ __forceinline__ unsigned int pk2(float lo, float hi) {
    return (unsigned int)f2bfu(lo) | ((unsigned int)f2bfu(hi) << 16);
}
__device__ __forceinline__ float bl16(unsigned int u) {
    union { unsigned int i; float f; } c; c.i = u << 16; return c.f;
}
__device__ __forceinline__ float bh16(unsigned int u) {
    union { unsigned int i; float f; } c; c.i = u & 0xffff0000u; return c.f;
}
__device__ __forceinline__ bf16x8 loadB_sw(const __hip_bfloat16* wsb, int frag, int lane) {
    return *(const bf16x8*)(wsb + (frag << 9) + (lane << 3));
}
__device__ __forceinline__ bf16x8 ldsFrag(const __hip_bfloat16* base, int frag, int lane) {
    return *(const bf16x8*)(base + (frag << 9) + (lane << 3));
}
__device__ __forceinline__ bf16x8 loadB_f32(const float* wf, int idx) {
    bf16x8 r;
    #pragma unroll
    for (int j = 0; j < 8; ++j) r[j] = (short)f2bfu(wf[idx + j]);
    return r;
}
__device__ __forceinline__ float gelu(float v) {
    return 0.5f * v * (1.f + erff(v * 0.70710678118654752f));
}

// ---------------------------------------------------------------- prep
__global__ __launch_bounds__(256) void prep_kernel(
    const float* __restrict__ qkv_w, const float* __restrict__ proj_w,
    const float* __restrict__ fc1_w, const float* __restrict__ fc2_w,
    const float* __restrict__ rpb,
    __hip_bfloat16* __restrict__ wsb, __hip_bfloat16* __restrict__ biasMb)
{
    int i = blockIdx.x * 256 + threadIdx.x;
    if (i < WS_BF16_N) {
        int f = i >> 9, lane = (i >> 3) & 63, j = i & 7;
        int l15 = lane & 15, g = lane >> 4;
        float v;
        if (f < FR_PROJ) {
            int ks = f % 3, nt = (f / 3) % 6, c = f / 18;
            v = qkv_w[(c * 96 + nt * 16 + l15) * 96 + ks * 32 + g * 8 + j];
            if (c == 0) v *= SCALE;
        } else if (f < FR_FC1) {
            int f2 = f - FR_PROJ, ks = f2 % 3, nt = f2 / 3;
            v = proj_w[(nt * 16 + l15) * 96 + ks * 32 + g * 8 + j];
        } else if (f < FR_FC2) {
            int f2 = f - FR_FC1, ks = f2 % 3, nt = (f2 / 3) % 4, hc = f2 / 12;
            v = fc1_w[(hc * 64 + nt * 16 + l15) * 96 + ks * 32 + g * 8 + j];
        } else {
            int f2 = f - FR_FC2, p = f2 & 1, nt = (f2 >> 1) % 6, hc = f2 / 12;
            v = fc2_w[(nt * 16 + l15) * 384 + hc * 64 + p * 32 + g * 8 + j];
        }
        wsb[i] = __float2bfloat16(v);
    } else if (i < WS_BF16_N + 37632) {
        int j = i - WS_BF16_N;
        int r = j & 3, lane = (j >> 2) & 63;
        int rest = j >> 8;
        int U = rest % 7; rest /= 7;
        int Tt = rest % 7, h = rest / 7;
        int t = Tt * 16 + (lane & 15);              if (t > 97) t = 97;
        int u = U * 16 + ((lane >> 4) << 2) + r;    if (u > 97) u = 97;
        biasMb[j] = __float2bfloat16(rpb[(pcode(t) - pcode(u) + 253) * 3 + h]);
    }
}

// ---------------------------------------------------------------- fused block
__global__ __launch_bounds__(512, 4) void fused_kernel(
    const float* __restrict__ x,
    const float* __restrict__ n1w, const float* __restrict__ n1b,
    const float* __restrict__ qkv_w, const float* __restrict__ qkv_b,
    const float* __restrict__ proj_w, const float* __restrict__ proj_b,
    const float* __restrict__ rpb,
    const float* __restrict__ n2w, const float* __restrict__ n2b,
    const float* __restrict__ w1, const float* __restrict__ b1,
    const float* __restrict__ w2, const float* __restrict__ b2,
    const __hip_bfloat16* __restrict__ wsb, const __hip_bfloat16* __restrict__ biasMb,
    int usews,
    float* __restrict__ out)
{
    // LDS carve: [0,23296) XS bf16[112][104]; [23296,46592) Kb bf16[112][104];
    // [46592,72704) VQ bf16 (QB[112][104] then vT[96][136]).
    // Wq staged at 23296 (18KB) during LN1 (Kb region free until k-chunk).
    // After bar4: S0=[23296,47872), S1=[47872,72448) weight staging buffers.
    __shared__ __align__(16) unsigned char LB[72704];
    __shared__ int rowbase[NTOK];
    __hip_bfloat16 (*XS)[104] = (__hip_bfloat16 (*)[104])LB;
    __hip_bfloat16 (*Kb)[104] = (__hip_bfloat16 (*)[104])(LB + 23296);
    __hip_bfloat16* VQ = (__hip_bfloat16*)(LB + 46592);
    __hip_bfloat16* S0 = (__hip_bfloat16*)(LB + 23296);   // also Wq staging
    __hip_bfloat16* S1 = (__hip_bfloat16*)(LB + 47872);

    const int wid = blockIdx.x, tid = threadIdx.x;
    const int lane = tid & 63, wv = tid >> 6;       // 8 waves
    const int l15 = lane & 15;
    const int g = lane >> 4;
    const int koff = g * 8;
    const int drow = g * 4;
    const bool oddg = (g >> 1) & 1;
    const int srcA = l15 + ((g & 1) << 5);
    const int srcB = srcA + 16;

    for (int t = tid; t < NTOK; t += 512) rowbase[t] = row_of(wid, t) * 96;
    for (int i = tid; i < 14 * 104; i += 512) {     // zero XS pad rows 98..111
        int r = 98 + i / 104, c = i % 104;
        XS[r][c] = __float2bfloat16(0.f);
    }
    // stage Wq (frags 0..17, 18KB) into Kb region (free until k-chunk)
    if (usews) {
        const int4* s = (const int4*)wsb;
        int4* d = (int4*)S0;
        for (int i = tid; i < 1152; i += 512) d[i] = s[i];
    }

    // ---- LN1 -> XS bf16 (one wave per token)
    {
        float w0 = n1w[lane], b0 = n1b[lane];
        float w1_ = (lane < 32) ? n1w[64 + lane] : 0.f;
        float b1_ = (lane < 32) ? n1b[64 + lane] : 0.f;
        for (int t = wv; t < NTOK; t += 8) {
            int base = row_of(wid, t) * 96;
            float v0 = x[base + lane];
            float v1 = (lane < 32) ? x[base + 64 + lane] : 0.f;
            float s = v0 + v1;
            #pragma unroll
            for (int m = 32; m; m >>= 1) s += __shfl_xor(s, m, 64);
            float mean = s * (1.f / 96.f);
            float e0 = v0 - mean;
            float e1 = (lane < 32) ? (v1 - mean) : 0.f;
            float ss = e0 * e0 + e1 * e1;
            #pragma unroll
            for (int m = 32; m; m >>= 1) ss += __shfl_xor(ss, m, 64);
            float rstd = rsqrtf(ss * (1.f / 96.f) + 1e-5f);
            XS[t][lane] = __float2bfloat16(e0 * rstd * w0 + b0);
            if (lane < 32)
                XS[t][64 + lane] = __float2bfloat16(e1 * rstd * w1_ + b1_);
        }
    }
    __syncthreads();                                   // bar0: XS + Wq staged

    // ---- chunk q: Q = XS @ Wq^T (B from LDS), C-frags -> QB bounce
    __hip_bfloat16* QB = &VQ[0];                       // [112][104]
    for (int tile = wv; tile < 42; tile += 8) {
        int m0 = (tile / 6) * 16, nt = tile % 6, n0 = nt * 16;
        f32x4 acc = {0.f, 0.f, 0.f, 0.f};
        #pragma unroll
        for (int ks = 0; ks < 3; ++ks) {
            bf16x8 a = *(const bf16x8*)&XS[m0 + l15][ks * 32 + koff];
            bf16x8 b = usews ? ldsFrag(S0, nt * 3 + ks, lane)
                             : loadB_f32(qkv_w, (n0 + l15) * 96 + ks * 32 + koff);
            acc = __builtin_amdgcn_mfma_f32_16x16x32_bf16(a, b, acc, 0, 0, 0);
        }
        float bb = qkv_b[n0 + l15];
        #pragma unroll
        for (int r = 0; r < 4; ++r) {
            float q = usews ? (acc[r] + bb * SCALE) : ((acc[r] + bb) * SCALE);
            QB[(m0 + drow + r) * 104 + n0 + l15] = __float2bfloat16(q);
        }
    }
    __syncthreads();                                   // bar1: QB ready, Wq dead

    // ---- Q preload to registers
    bf16x8 qf[3];
    #pragma unroll
    for (int i = 0; i < 3; ++i) {
        int task = wv + 8 * i;
        if (task < 21) {
            int s_ = task / 3, h_ = task - 3 * s_;
            qf[i] = *(const bf16x8*)&QB[(s_ * 16 + l15) * 104 + h_ * 32 + koff];
        }
    }
    __syncthreads();                                   // bar2: QB dead -> vT region

    // ---- vT tail zero + chunks k, v (weights from global ws; no free LDS window)
    __hip_bfloat16* vT = &VQ[0];                       // [96][136]
    for (int i = tid; i < 96 * 38; i += 512) {
        int r = i / 38, c = 98 + (i - r * 38);
        vT[r * 136 + c] = __float2bfloat16(0.f);
    }
    for (int c = 1; c < 3; ++c) {
        for (int tile = wv; tile < 42; tile += 8) {
            int m0 = (tile / 6) * 16, nt = tile % 6, n0 = nt * 16;
            f32x4 acc = {0.f, 0.f, 0.f, 0.f};
            #pragma unroll
            for (int ks = 0; ks < 3; ++ks) {
                bf16x8 a = *(const bf16x8*)&XS[m0 + l15][ks * 32 + koff];
                bf16x8 b = usews ? loadB_sw(wsb, (c * 6 + nt) * 3 + ks, lane)
                                 : loadB_f32(qkv_w + c * 9216,
                                             (n0 + l15) * 96 + ks * 32 + koff);
                acc = __builtin_amdgcn_mfma_f32_16x16x32_bf16(a, b, acc, 0, 0, 0);
            }
            float bb = qkv_b[c * 96 + n0 + l15];
            if (c == 1) {
                #pragma unroll
                for (int r = 0; r < 4; ++r)
                    Kb[m0 + drow + r][n0 + l15] = __float2bfloat16(acc[r] + bb);
            } else {
                unsigned int d0 = pk2(acc[0] + bb, acc[1] + bb);
                unsigned int d1 = pk2(acc[2] + bb, acc[3] + bb);
                int u0 = m0 + drow;
                if (u0 < NTOK) {
                    unsigned int* p = (unsigned int*)&vT[(n0 + l15) * 136 + u0];
                    p[0] = d0;
                    if (u0 + 2 < NTOK) p[1] = d1;
                }
            }
        }
    }
    __syncthreads();                                   // bar3: Kb, vT ready

    // ---- head loop, barrier-free: (strip,head) tasks
    #pragma unroll 1
    for (int i = 0; i < 3; ++i) {
        int task = wv + 8 * i;
        if (task >= 21) break;
        int strip = task / 3, h = task - 3 * strip;

        f32x4 s[7];
        #pragma unroll
        for (int U = 0; U < 7; ++U) {
            bf16x8 ak = *(const bf16x8*)&Kb[U * 16 + l15][h * 32 + koff];
            f32x4 z = {0.f, 0.f, 0.f, 0.f};
            s[U] = __builtin_amdgcn_mfma_f32_16x16x32_bf16(ak, qf[i], z, 0, 0, 0);
        }
        if (usews) {
            const __hip_bfloat16* bmb = biasMb + (((h * 7 + strip) * 7) << 8) + (lane << 2);
            #pragma unroll
            for (int U = 0; U < 7; ++U) {
                uint2 bv = *(const uint2*)(bmb + (U << 8));
                s[U][0] += bl16(bv.x); s[U][1] += bh16(bv.x);
                s[U][2] += bl16(bv.y); s[U][3] += bh16(bv.y);
            }
        } else {
            int tq = strip * 16 + l15; if (tq > 97) tq = 97;
            int pt = pcode(tq);
            #pragma unroll
            for (int U = 0; U < 7; ++U)
                #pragma unroll
                for (int r = 0; r < 4; ++r) {
                    int u = U * 16 + drow + r; if (u > 97) u = 97;
                    s[U][r] += rpb[(pt - pcode(u) + 253) * 3 + h];
                }
        }
        if (drow > 0) { s[6][0] = -1e30f; s[6][1] = -1e30f; }
        s[6][2] = -1e30f; s[6][3] = -1e30f;
        f32x4 sumv = {0.f, 0.f, 0.f, 0.f};
        #pragma unroll
        for (int U = 0; U < 7; ++U) {
            #pragma unroll
            for (int r = 0; r < 4; ++r) { s[U][r] = __expf(s[U][r]); sumv[r] += s[U][r]; }
        }
        float hs = sumv[0] + sumv[1] + sumv[2] + sumv[3];
        hs += __shfl_xor(hs, 16, 64);
        hs += __shfl_xor(hs, 32, 64);
        float inv = 1.f / hs;
        unsigned int dwl[7], dwh[7];
        #pragma unroll
        for (int U = 0; U < 7; ++U) {
            dwl[U] = pk2(s[U][0] * inv, s[U][1] * inv);
            dwh[U] = pk2(s[U][2] * inv, s[U][3] * inv);
        }
        f32x4 acc0 = {0.f, 0.f, 0.f, 0.f}, acc1 = {0.f, 0.f, 0.f, 0.f};
        #pragma unroll
        for (int ks = 0; ks < 4; ++ks) {
            unsigned int D0, D1, D2, D3;
            if (ks < 3) {
                unsigned int e0 = __shfl((int)dwl[2 * ks], srcA, 64);
                unsigned int o0 = __shfl((int)dwl[2 * ks + 1], srcA, 64);
                unsigned int e1 = __shfl((int)dwh[2 * ks], srcA, 64);
                unsigned int o1 = __shfl((int)dwh[2 * ks + 1], srcA, 64);
                unsigned int e2 = __shfl((int)dwl[2 * ks], srcB, 64);
                unsigned int o2 = __shfl((int)dwl[2 * ks + 1], srcB, 64);
                unsigned int e3 = __shfl((int)dwh[2 * ks], srcB, 64);
                unsigned int o3 = __shfl((int)dwh[2 * ks + 1], srcB, 64);
                D0 = oddg ? o0 : e0; D1 = oddg ? o1 : e1;
                D2 = oddg ? o2 : e2; D3 = oddg ? o3 : e3;
            } else {
                unsigned int t0 = __shfl((int)dwl[6], srcA, 64);
                unsigned int t1 = __shfl((int)dwh[6], srcA, 64);
                unsigned int t2 = __shfl((int)dwl[6], srcB, 64);
                unsigned int t3 = __shfl((int)dwh[6], srcB, 64);
                D0 = (g < 2) ? t0 : 0u; D1 = (g < 2) ? t1 : 0u;
                D2 = (g < 2) ? t2 : 0u; D3 = (g < 2) ? t3 : 0u;
            }
            union { unsigned int d[4]; bf16x8 v; } af;
            af.d[0] = D0; af.d[1] = D1; af.d[2] = D2; af.d[3] = D3;
            bf16x8 b0 = *(const bf16x8*)&vT[(h * 32 + l15) * 136 + ks * 32 + koff];
            bf16x8 b1_ = *(const bf16x8*)&vT[(h * 32 + 16 + l15) * 136 + ks * 32 + koff];
            acc0 = __builtin_amdgcn_mfma_f32_16x16x32_bf16(af.v, b0, acc0, 0, 0, 0);
            acc1 = __builtin_amdgcn_mfma_f32_16x16x32_bf16(af.v, b1_, acc1, 0, 0, 0);
        }
        #pragma unroll
        for (int r = 0; r < 4; ++r) {
            XS[strip * 16 + drow + r][h * 32 + l15]      = __float2bfloat16(acc0[r]);
            XS[strip * 16 + drow + r][h * 32 + 16 + l15] = __float2bfloat16(acc1[r]);
        }
    }
    __syncthreads();                                   // bar4: attn-out ready; Kb/vT dead

    // ---- stage proj -> S0 and fc1/fc2[hc=0] -> S1 (all waves)
    if (usews) {
        const int4* sp = (const int4*)(wsb + (FR_PROJ << 9));
        int4* d0 = (int4*)S0;
        for (int i = tid; i < 1152; i += 512) d0[i] = sp[i];
        const int4* s1 = (const int4*)(wsb + (FR_FC1 << 9));
        const int4* s2 = (const int4*)(wsb + (FR_FC2 << 9));
        int4* d1 = (int4*)S1;
        for (int i = tid; i < 768; i += 512) d1[i] = s1[i];
        for (int i = tid; i < 768; i += 512) d1[768 + i] = s2[i];
    }
    __syncthreads();                                   // bar5: staged

    // ==== per-strip tail (waves 0..6); wave 7 = producer in the hc loop ====
    float res[6][4];
    f32x4 yacc[6];
    const int m0 = wv * 16;
    if (wv < 7) {
        // proj GEMM (B from S0) + x residual -> res regs; LN2 stats on the fly
        f32x4 sAcc = {0.f, 0.f, 0.f, 0.f}, sqAcc = {0.f, 0.f, 0.f, 0.f};
        #pragma unroll
        for (int nt = 0; nt < 6; ++nt) {
            f32x4 acc = {0.f, 0.f, 0.f, 0.f};
            #pragma unroll
            for (int ks = 0; ks < 3; ++ks) {
                bf16x8 a = *(const bf16x8*)&XS[m0 + l15][ks * 32 + koff];
                bf16x8 b = usews ? ldsFrag(S0, nt * 3 + ks, lane)
                                 : loadB_f32(proj_w, (nt * 16 + l15) * 96 + ks * 32 + koff);
                acc = __builtin_amdgcn_mfma_f32_16x16x32_bf16(a, b, acc, 0, 0, 0);
            }
            float pb = proj_b[nt * 16 + l15];
            #pragma unroll
            for (int r = 0; r < 4; ++r) {
                int t = m0 + drow + r;
                float rv = (t < NTOK) ? (acc[r] + pb + x[rowbase[t] + nt * 16 + l15]) : 0.f;
                res[nt][r] = rv;
                sAcc[r] += rv; sqAcc[r] += rv * rv;
            }
        }
        #pragma unroll
        for (int r = 0; r < 4; ++r) {
            float s = sAcc[r], sq = sqAcc[r];
            #pragma unroll
            for (int m = 1; m < 16; m <<= 1) {
                s  += __shfl_xor(s, m, 64);
                sq += __shfl_xor(sq, m, 64);
            }
            float mean = s * (1.f / 96.f);
            float var = sq * (1.f / 96.f) - mean * mean;
            float rstd = rsqrtf(var + 1e-5f);
            #pragma unroll
            for (int nt = 0; nt < 6; ++nt) {
                int cc = nt * 16 + l15;
                XS[m0 + drow + r][cc] =
                    __float2bfloat16((res[nt][r] - mean) * rstd * n2w[cc] + n2b[cc]);
            }
        }
        #pragma unroll
        for (int nt = 0; nt < 6; ++nt) yacc[nt] = (f32x4){0.f, 0.f, 0.f, 0.f};
    }

    // MLP loop: per hc, waves 0-6 compute from buf(hc); wave 7 stages hc+1
    #pragma unroll 1
    for (int hc = 0; hc < 6; ++hc) {
        __syncthreads();   // prev stage visible; prev reads of target buf done
        if (wv == 7) {
            if (usews && hc < 5) {
                int4* d = (int4*)((hc & 1) ? S1 : S0);   // hc+1's read buffer
                const int4* s1 = (const int4*)(wsb + ((FR_FC1 + (hc + 1) * 12) << 9));
                const int4* s2 = (const int4*)(wsb + ((FR_FC2 + (hc + 1) * 12) << 9));
                for (int i = lane; i < 768; i += 64) d[i] = s1[i];
                for (int i = lane; i < 768; i += 64) d[768 + i] = s2[i];
            }
        } else {
            const __hip_bfloat16* WB = (hc & 1) ? S0 : S1;
            #pragma unroll
            for (int p = 0; p < 2; ++p) {
                f32x4 s0 = {0.f, 0.f, 0.f, 0.f}, s1v = {0.f, 0.f, 0.f, 0.f};
                #pragma unroll
                for (int ks = 0; ks < 3; ++ks) {
                    bf16x8 xb = *(const bf16x8*)&XS[m0 + l15][ks * 32 + koff];
                    bf16x8 aw0 = usews ? ldsFrag(WB, (2 * p) * 3 + ks, lane)
                                       : loadB_f32(w1, (hc * 64 + 2 * p * 16 + l15) * 96 + ks * 32 + koff);
                    bf16x8 aw1 = usews ? ldsFrag(WB, (2 * p + 1) * 3 + ks, lane)
                                       : loadB_f32(w1, (hc * 64 + (2 * p + 1) * 16 + l15) * 96 + ks * 32 + koff);
                    s0  = __builtin_amdgcn_mfma_f32_16x16x32_bf16(aw0, xb, s0, 0, 0, 0);
                    s1v = __builtin_amdgcn_mfma_f32_16x16x32_bf16(aw1, xb, s1v, 0, 0, 0);
                }
                f32x4 bv0 = *(const f32x4*)&b1[hc * 64 + 2 * p * 16 + drow];
                f32x4 bv1 = *(const f32x4*)&b1[hc * 64 + (2 * p + 1) * 16 + drow];
                unsigned int dl0 = pk2(gelu(s0[0] + bv0[0]), gelu(s0[1] + bv0[1]));
                unsigned int dh0 = pk2(gelu(s0[2] + bv0[2]), gelu(s0[3] + bv0[3]));
                unsigned int dl1 = pk2(gelu(s1v[0] + bv1[0]), gelu(s1v[1] + bv1[1]));
                unsigned int dh1 = pk2(gelu(s1v[2] + bv1[2]), gelu(s1v[3] + bv1[3]));

                unsigned int e0 = __shfl((int)dl0, srcA, 64);
                unsigned int o0 = __shfl((int)dl1, srcA, 64);
                unsigned int e1 = __shfl((int)dh0, srcA, 64);
                unsigned int o1 = __shfl((int)dh1, srcA, 64);
                unsigned int e2 = __shfl((int)dl0, srcB, 64);
                unsigned int o2 = __shfl((int)dl1, srcB, 64);
                unsigned int e3 = __shfl((int)dh0, srcB, 64);
                unsigned int o3 = __shfl((int)dh1, srcB, 64);
                union { unsigned int d[4]; bf16x8 v; } af;
                af.d[0] = oddg ? o0 : e0;
                af.d[1] = oddg ? o1 : e1;
                af.d[2] = oddg ? o2 : e2;
                af.d[3] = oddg ? o3 : e3;
                #pragma unroll
                for (int nt = 0; nt < 6; ++nt) {
                    bf16x8 bw = usews ? ldsFrag(WB, 12 + nt * 2 + p, lane)
                                      : loadB_f32(w2, (nt * 16 + l15) * 384 + hc * 64 + p * 32 + koff);
                    yacc[nt] = __builtin_amdgcn_mfma_f32_16x16x32_bf16(af.v, bw, yacc[nt], 0, 0, 0);
                }
            }
        }
    }

    // ---- final: out = res + y + b2 (direct stores, 64B segments per instr)
    if (wv < 7) {
        #pragma unroll
        for (int nt = 0; nt < 6; ++nt) {
            float bb2 = b2[nt * 16 + l15];
            #pragma unroll
            for (int r = 0; r < 4; ++r) {
                int t = m0 + drow + r;
                if (t < NTOK)
                    out[rowbase[t] + nt * 16 + l15] = res[nt][r] + yacc[nt][r] + bb2;
            }
        }
    }
}

extern "C" void kernel_launch(void* const* d_in, const int* in_sizes, int n_in,
                              void* d_out, int out_size, void* d_ws, size_t ws_size,
                              hipStream_t stream) {
    const float* x      = (const float*)d_in[0];
    const float* n1w    = (const float*)d_in[1];
    const float* n1b    = (const float*)d_in[2];
    const float* qkv_w  = (const float*)d_in[3];
    const float* qkv_b  = (const float*)d_in[4];
    const float* proj_w = (const float*)d_in[5];
    const float* proj_b = (const float*)d_in[6];
    const float* rpb    = (const float*)d_in[7];
    const float* n2w    = (const float*)d_in[8];
    const float* n2b    = (const float*)d_in[9];
    const float* fc1_w  = (const float*)d_in[10];
    const float* fc1_b  = (const float*)d_in[11];
    const float* fc2_w  = (const float*)d_in[12];
    const float* fc2_b  = (const float*)d_in[13];
    float* out = (float*)d_out;

    const int usews = (ws_size >= (size_t)WS_NEED) ? 1 : 0;
    __hip_bfloat16* wsb = (__hip_bfloat16*)d_ws;
    __hip_bfloat16* biasMb = (__hip_bfloat16*)((char*)d_ws + WS_BIASM_BYTE);

    if (usews)
        prep_kernel<<<(WS_BF16_N + 37632 + 255) / 256, 256, 0, stream>>>(
            qkv_w, proj_w, fc1_w, fc2_w, rpb, wsb, biasMb);

    fused_kernel<<<2048, 512, 0, stream>>>(x, n1w, n1b, qkv_w, qkv_b,
                                           proj_w, proj_b, rpb,
                                           n2w, n2b, fc1_w, fc1_b, fc2_w, fc2_b,
                                           wsb, biasMb, usews, out);
}